// Round 1
// baseline (6041.388 us; speedup 1.0000x reference)
//
#include <hip/hip_runtime.h>

#define TT 64   // timesteps
#define LL 64   // layers
#define BB 128  // batch
#define HH 64   // hidden
#define GG 4    // workgroups per layer (column split)
#define PP 4    // parity (rotating) h buffers

// Workspace layout (floats unless noted):
//   done    : int[LL*TT]                  (flag counters, 0..GG)
//   hbuf    : float[PP][LL][HH][BB]       (transposed h: [k][b], b contiguous)
//   htop    : float[TT][HH][BB]           (layer-63 h history, for epilogue)
//   partials: float[TT]

__device__ __forceinline__ float sigm(float x)  { return 1.f / (1.f + __expf(-x)); }
__device__ __forceinline__ float tanh_f(float x){ return 2.f / (1.f + __expf(-2.f*x)) - 1.f; }

__global__ __launch_bounds__(256, 1) void init_zero(int* done, float* hbuf3) {
    int i = blockIdx.x * 256 + threadIdx.x;
    if (i < LL * TT) done[i] = 0;
    const int n = LL * HH * BB;  // parity-3 buffer (t==0 reads zeros from here)
    for (int j = i; j < n; j += gridDim.x * 256) hbuf3[j] = 0.f;
}

__global__ __launch_bounds__(256, 1) void lstm_pipeline(
    const float* __restrict__ x,   // [B][T][1]
    const float* __restrict__ W0,  // [65][256]
    const float* __restrict__ b0,  // [256]
    const float* __restrict__ Wl,  // [63][128][256]
    const float* __restrict__ bl,  // [63][256]
    int* __restrict__ done,
    float* __restrict__ hbuf,
    float* __restrict__ htop)
{
    const int l   = blockIdx.x >> 2;   // layer
    const int g   = blockIdx.x & 3;    // column-group within layer
    const int tid = threadIdx.x;
    const int ct  = tid >> 5;          // 0..7  : column tile (8 cols = 2 units x 4 gates)
    const int bt  = tid & 31;          // 0..31 : batch tile (4 b's)

    // LDS: weights reordered so each thread's 8 columns are contiguous.
    // local col c' = uu*4 + gate, global col = gate*64 + g*16 + uu
    __shared__ float wsm[128][64];
    __shared__ float hT[128][132];     // [k][b], +4 pad keeps b128 alignment, breaks conflicts

    const float* Wsrc  = l ? (Wl + (size_t)(l - 1) * 128 * 256) : W0;
    const int    krows = l ? 128 : 65;
    for (int idx = tid; idx < krows * 64; idx += 256) {
        int k = idx >> 6, cp = idx & 63;
        wsm[k][cp] = Wsrc[k * 256 + (cp & 3) * 64 + g * 16 + (cp >> 2)];
    }
    const float* bsrc = l ? (bl + (l - 1) * 256) : b0;
    float bias[8];
#pragma unroll
    for (int j = 0; j < 8; ++j) {
        int cp = ct * 8 + j;
        bias[j] = bsrc[(cp & 3) * 64 + g * 16 + (cp >> 2)];
    }
    float cst[2][4] = {};  // private c-state: 2 units x 4 batch
    __syncthreads();

    for (int t = 0; t < TT; ++t) {
        // ---- wait for: input from below, own h(t-1), and buffer-reuse safety ----
        if (tid == 0) {
            if (l > 0)
                while (__hip_atomic_load(&done[(l - 1) * TT + t], __ATOMIC_ACQUIRE,
                                         __HIP_MEMORY_SCOPE_AGENT) < GG)
                    __builtin_amdgcn_s_sleep(1);
            if (t > 0)
                while (__hip_atomic_load(&done[l * TT + (t - 1)], __ATOMIC_ACQUIRE,
                                         __HIP_MEMORY_SCOPE_AGENT) < GG)
                    __builtin_amdgcn_s_sleep(1);
            if (l < LL - 1 && t >= PP)  // readers of the parity slot we are about to overwrite
                while (__hip_atomic_load(&done[(l + 1) * TT + (t - PP)], __ATOMIC_ACQUIRE,
                                         __HIP_MEMORY_SCOPE_AGENT) < GG)
                    __builtin_amdgcn_s_sleep(1);
        }
        __syncthreads();
        __threadfence();  // acquire: make producers' h stores visible (cross-XCD)

        // ---- stage h (transposed layout [k][b]) into LDS ----
        const float* own = (t == 0)
            ? (hbuf + ((size_t)3 * LL + l) * HH * BB)                       // zeros
            : (l == LL - 1 ? (htop + (size_t)(t - 1) * HH * BB)
                           : (hbuf + ((size_t)((t - 1) & 3) * LL + l) * HH * BB));
        if (l == 0) {
            if (tid < BB) hT[0][tid] = x[tid * TT + t];
            for (int idx = tid; idx < 2048; idx += 256) {
                int k = idx >> 5, b4 = (idx & 31) << 2;
                *(float4*)&hT[1 + k][b4] = *(const float4*)(own + k * BB + b4);
            }
        } else {
            const float* below = hbuf + ((size_t)(t & 3) * LL + (l - 1)) * HH * BB;
            for (int idx = tid; idx < 2048; idx += 256) {
                int k = idx >> 5, b4 = (idx & 31) << 2;
                *(float4*)&hT[k][b4]      = *(const float4*)(below + k * BB + b4);
                *(float4*)&hT[64 + k][b4] = *(const float4*)(own + k * BB + b4);
            }
        }
        __syncthreads();

        // ---- GEMM: z[b, c'] for 4 b x 8 c' per thread ----
        float acc[8][4] = {};
        for (int k = 0; k < krows; ++k) {
            float4 hv = *(const float4*)&hT[k][bt << 2];
            float4 wa = *(const float4*)&wsm[k][ct << 3];
            float4 wb = *(const float4*)&wsm[k][(ct << 3) + 4];
            float hvv[4] = {hv.x, hv.y, hv.z, hv.w};
            float wvv[8] = {wa.x, wa.y, wa.z, wa.w, wb.x, wb.y, wb.z, wb.w};
#pragma unroll
            for (int j = 0; j < 8; ++j)
#pragma unroll
                for (int i = 0; i < 4; ++i)
                    acc[j][i] = fmaf(wvv[j], hvv[i], acc[j][i]);
        }

        // ---- elementwise LSTM cell + store h2 (transposed [u][b]) ----
        float* dst = (l == LL - 1) ? (htop + (size_t)t * HH * BB)
                                   : (hbuf + ((size_t)(t & 3) * LL + l) * HH * BB);
#pragma unroll
        for (int ju = 0; ju < 2; ++ju) {
            float h2[4];
#pragma unroll
            for (int i = 0; i < 4; ++i) {
                float zi = acc[ju * 4 + 0][i] + bias[ju * 4 + 0];
                float zj = acc[ju * 4 + 1][i] + bias[ju * 4 + 1];
                float zf = acc[ju * 4 + 2][i] + bias[ju * 4 + 2];
                float zo = acc[ju * 4 + 3][i] + bias[ju * 4 + 3];
                float c2 = cst[ju][i] * sigm(zf) + sigm(zi) * tanh_f(zj);
                cst[ju][i] = c2;
                h2[i] = tanh_f(c2) * sigm(zo);
            }
            int u = g * 16 + ct * 2 + ju;
            float4 h4 = {h2[0], h2[1], h2[2], h2[3]};
            *(float4*)(dst + u * BB + (bt << 2)) = h4;
        }
        __threadfence();   // release our h stores (cross-XCD visibility)
        __syncthreads();   // all threads' stores fenced before the flag
        if (tid == 0)
            __hip_atomic_fetch_add(&done[l * TT + t], 1, __ATOMIC_RELEASE,
                                   __HIP_MEMORY_SCOPE_AGENT);
    }
}

__global__ __launch_bounds__(128, 1) void epilogue(
    const float* __restrict__ htop, const float* __restrict__ Wd,
    const float* __restrict__ bd, const float* __restrict__ labels,
    float* __restrict__ out, float* __restrict__ partials)
{
    int t = blockIdx.x, b = threadIdx.x;  // 64 blocks x 128 threads
    float s = 0.f;
    for (int h = 0; h < HH; ++h)
        s = fmaf(htop[(size_t)t * HH * BB + h * BB + b], Wd[t * HH + h], s);
    s += bd[t];
    s = fmaxf(s, 0.f);
    out[b * TT + t] = s;                    // pred is [B][T][1], b-major
    float d = labels[b * TT + t] - s;
    float e = d * d;
#pragma unroll
    for (int off = 32; off > 0; off >>= 1) e += __shfl_down(e, off, 64);
    __shared__ float ws2[2];
    if ((b & 63) == 0) ws2[b >> 6] = e;
    __syncthreads();
    if (b == 0) partials[t] = ws2[0] + ws2[1];
}

__global__ __launch_bounds__(64, 1) void finalize(const float* __restrict__ partials,
                                                  float* __restrict__ out) {
    int i = threadIdx.x;
    float v = partials[i];
#pragma unroll
    for (int off = 32; off > 0; off >>= 1) v += __shfl_down(v, off, 64);
    if (i == 0) out[BB * TT] = v * (1.f / (BB * TT));
}

extern "C" void kernel_launch(void* const* d_in, const int* in_sizes, int n_in,
                              void* d_out, int out_size, void* d_ws, size_t ws_size,
                              hipStream_t stream) {
    const float* x      = (const float*)d_in[0];
    const float* labels = (const float*)d_in[1];
    const float* W0     = (const float*)d_in[2];
    const float* b0     = (const float*)d_in[3];
    const float* Wl     = (const float*)d_in[4];
    const float* bl     = (const float*)d_in[5];
    const float* Wd     = (const float*)d_in[6];
    const float* bd     = (const float*)d_in[7];
    float* out = (float*)d_out;

    int*   done     = (int*)d_ws;
    float* hbuf     = (float*)d_ws + 4096;
    float* htop     = hbuf + (size_t)PP * LL * HH * BB;
    float* partials = htop + (size_t)TT * HH * BB;

    init_zero<<<512, 256, 0, stream>>>(done, hbuf + (size_t)3 * LL * HH * BB);
    lstm_pipeline<<<256, 256, 0, stream>>>(x, W0, b0, Wl, bl, done, hbuf, htop);
    epilogue<<<64, 128, 0, stream>>>(htop, Wd, bd, labels, out, partials);
    finalize<<<1, 64, 0, stream>>>(partials, out);
}

// Round 2
// 1811.826 us; speedup vs baseline: 3.3344x; 3.3344x over previous
//
#include <hip/hip_runtime.h>

#define TT 64   // timesteps
#define LL 64   // layers
#define BB 128  // batch
#define HH 64   // hidden
#define GG 4    // workgroups per layer (column split)
#define PP 4    // parity (rotating) h buffers

// Workspace layout:
//   done    : int[LL*TT]              (flag counters, 0..GG)
//   hbuf    : float[PP][LL][HH][BB]   (transposed h: [unit][b], b contiguous)
//   htop    : float[TT][HH][BB]       (layer-63 h history, for epilogue)
//   partials: float[TT]
//
// Coherence scheme (gfx950, per-XCD L2 NOT coherent):
//   - all cross-WG h data + flags move via RELAXED agent-scope atomics
//     (compile to global ops with sc1 -> serviced at the Infinity Cache,
//     bypassing the stale-prone local L2). NO fences -> no buffer_inv/wbl2.
//   - release ordering: s_waitcnt(0) after the h stores, before the flag add.
//   - acquire ordering: flag poll + __syncthreads precede the sc1 data loads.

__device__ __forceinline__ float sigm(float x)  { return 1.f / (1.f + __expf(-x)); }
__device__ __forceinline__ float tanh_f(float x){ return 2.f / (1.f + __expf(-2.f*x)) - 1.f; }

__device__ __forceinline__ float gload(const float* p) {
    return __hip_atomic_load(p, __ATOMIC_RELAXED, __HIP_MEMORY_SCOPE_AGENT);
}
__device__ __forceinline__ void gstore(float* p, float v) {
    __hip_atomic_store(p, v, __ATOMIC_RELAXED, __HIP_MEMORY_SCOPE_AGENT);
}
__device__ __forceinline__ int fload(const int* p) {
    return __hip_atomic_load(p, __ATOMIC_RELAXED, __HIP_MEMORY_SCOPE_AGENT);
}

__global__ __launch_bounds__(256, 1) void init_zero(int* done) {
    int i = blockIdx.x * 256 + threadIdx.x;
    if (i < LL * TT) done[i] = 0;
}

__global__ __launch_bounds__(512, 1) void lstm_pipeline(
    const float* __restrict__ x,   // [B][T][1]
    const float* __restrict__ W0,  // [65][256]
    const float* __restrict__ b0,  // [256]
    const float* __restrict__ Wl,  // [63][128][256]
    const float* __restrict__ bl,  // [63][256]
    int* __restrict__ done,
    float* __restrict__ hbuf,
    float* __restrict__ htop)
{
    const int l   = blockIdx.x >> 2;   // layer
    const int g   = blockIdx.x & 3;    // column-group within layer (16 units)
    const int tid = threadIdx.x;
    const int ct  = tid >> 5;          // 0..15 : local unit (4 gate-cols each)
    const int bt  = tid & 31;          // 0..31 : batch tile (4 b's)

    // Weights reordered: local col cp = unit*4 + gate; global col = gate*64 + g*16 + unit
    __shared__ float wsm[128][64];     // 32 KB
    __shared__ float hOwn[64][132];    // 33.8 KB (+4 pad)
    __shared__ float hBelow[64][132];  // 33.8 KB

    const float* Wsrc  = l ? (Wl + (size_t)(l - 1) * 128 * 256) : W0;
    const int    krows = l ? 128 : 65;
    for (int idx = tid; idx < krows * 64; idx += 512) {
        int k = idx >> 6, cp = idx & 63;
        wsm[k][cp] = Wsrc[k * 256 + (cp & 3) * 64 + g * 16 + (cp >> 2)];
    }
    const float* bsrc = l ? (bl + (l - 1) * 256) : b0;
    float bias[4];
#pragma unroll
    for (int gate = 0; gate < 4; ++gate)
        bias[gate] = bsrc[gate * 64 + g * 16 + ct];

    float cst[4] = {};                 // c-state: 1 unit x 4 batch
    const int ownBase = l ? 64 : 1;    // wsm row where own-h k-range starts
    __syncthreads();

    for (int t = 0; t < TT; ++t) {
        float acc[4][4] = {};          // [gate][batch]

        // ---------- Phase A: own-h(t-1) half (off the layer-below critical path) ----
        if (t > 0) {
            if (tid == 0)
                while (fload(&done[l * TT + (t - 1)]) < GG) {}
            __syncthreads();
            const float* own = (l == LL - 1)
                ? (htop + (size_t)(t - 1) * HH * BB)
                : (hbuf + ((size_t)((t - 1) & 3) * LL + l) * HH * BB);
            for (int idx = tid; idx < HH * BB; idx += 512)
                hOwn[idx >> 7][idx & 127] = gload(own + idx);
            __syncthreads();
#pragma unroll 4
            for (int k = 0; k < 64; ++k) {
                float4 hv = *(const float4*)&hOwn[k][bt << 2];
                float4 wv = *(const float4*)&wsm[ownBase + k][ct << 2];
                float h4[4] = {hv.x, hv.y, hv.z, hv.w};
                float w4[4] = {wv.x, wv.y, wv.z, wv.w};
#pragma unroll
                for (int j = 0; j < 4; ++j)
#pragma unroll
                    for (int i = 0; i < 4; ++i)
                        acc[j][i] = fmaf(w4[j], h4[i], acc[j][i]);
            }
            __syncthreads();  // hOwn reuse safety before next-iter staging (cheap)
        }

        // ---------- Phase B: below-h(t) half (critical path) ----------
        if (tid == 0) {
            if (l > 0)
                while (fload(&done[(l - 1) * TT + t]) < GG) {}
            if (l < LL - 1 && t >= PP)   // readers of the parity slot we overwrite
                while (fload(&done[(l + 1) * TT + (t - PP)]) < GG) {}
        }
        __syncthreads();

        if (l == 0) {
            if (tid < BB) hBelow[0][tid] = x[tid * TT + t];
        } else {
            const float* below = hbuf + ((size_t)(t & 3) * LL + (l - 1)) * HH * BB;
            for (int idx = tid; idx < HH * BB; idx += 512)
                hBelow[idx >> 7][idx & 127] = gload(below + idx);
        }
        __syncthreads();

        if (l == 0) {
            float4 xv = *(const float4*)&hBelow[0][bt << 2];
            float4 wv = *(const float4*)&wsm[0][ct << 2];
            float h4[4] = {xv.x, xv.y, xv.z, xv.w};
            float w4[4] = {wv.x, wv.y, wv.z, wv.w};
#pragma unroll
            for (int j = 0; j < 4; ++j)
#pragma unroll
                for (int i = 0; i < 4; ++i)
                    acc[j][i] = fmaf(w4[j], h4[i], acc[j][i]);
        } else {
#pragma unroll 4
            for (int k = 0; k < 64; ++k) {
                float4 hv = *(const float4*)&hBelow[k][bt << 2];
                float4 wv = *(const float4*)&wsm[k][ct << 2];
                float h4[4] = {hv.x, hv.y, hv.z, hv.w};
                float w4[4] = {wv.x, wv.y, wv.z, wv.w};
#pragma unroll
                for (int j = 0; j < 4; ++j)
#pragma unroll
                    for (int i = 0; i < 4; ++i)
                        acc[j][i] = fmaf(w4[j], h4[i], acc[j][i]);
            }
        }

        // ---------- elementwise LSTM cell + h2 store ----------
        float* dst = (l == LL - 1) ? (htop + (size_t)t * HH * BB)
                                   : (hbuf + ((size_t)(t & 3) * LL + l) * HH * BB);
        const int u = g * 16 + ct;
        float h2[4];
#pragma unroll
        for (int i = 0; i < 4; ++i) {
            float zi = acc[0][i] + bias[0];
            float zj = acc[1][i] + bias[1];
            float zf = acc[2][i] + bias[2];
            float zo = acc[3][i] + bias[3];
            float c2 = cst[i] * sigm(zf) + sigm(zi) * tanh_f(zj);
            cst[i] = c2;
            h2[i] = tanh_f(c2) * sigm(zo);
        }
#pragma unroll
        for (int i = 0; i < 4; ++i)
            gstore(dst + u * BB + (bt << 2) + i, h2[i]);

        __builtin_amdgcn_s_waitcnt(0);   // release: h stores reached IC
        __syncthreads();                 // all 512 threads' stores drained
        if (tid == 0)
            __hip_atomic_fetch_add(&done[l * TT + t], 1, __ATOMIC_RELAXED,
                                   __HIP_MEMORY_SCOPE_AGENT);
    }
}

__global__ __launch_bounds__(128, 1) void epilogue(
    const float* __restrict__ htop, const float* __restrict__ Wd,
    const float* __restrict__ bd, const float* __restrict__ labels,
    float* __restrict__ out, float* __restrict__ partials)
{
    int t = blockIdx.x, b = threadIdx.x;  // 64 blocks x 128 threads
    float s = 0.f;
    for (int h = 0; h < HH; ++h)
        s = fmaf(htop[(size_t)t * HH * BB + h * BB + b], Wd[t * HH + h], s);
    s += bd[t];
    s = fmaxf(s, 0.f);
    out[b * TT + t] = s;                  // pred is [B][T][1], b-major
    float d = labels[b * TT + t] - s;
    float e = d * d;
#pragma unroll
    for (int off = 32; off > 0; off >>= 1) e += __shfl_down(e, off, 64);
    __shared__ float ws2[2];
    if ((b & 63) == 0) ws2[b >> 6] = e;
    __syncthreads();
    if (b == 0) partials[t] = ws2[0] + ws2[1];
}

__global__ __launch_bounds__(64, 1) void finalize(const float* __restrict__ partials,
                                                  float* __restrict__ out) {
    int i = threadIdx.x;
    float v = partials[i];
#pragma unroll
    for (int off = 32; off > 0; off >>= 1) v += __shfl_down(v, off, 64);
    if (i == 0) out[BB * TT] = v * (1.f / (BB * TT));
}

extern "C" void kernel_launch(void* const* d_in, const int* in_sizes, int n_in,
                              void* d_out, int out_size, void* d_ws, size_t ws_size,
                              hipStream_t stream) {
    const float* x      = (const float*)d_in[0];
    const float* labels = (const float*)d_in[1];
    const float* W0     = (const float*)d_in[2];
    const float* b0     = (const float*)d_in[3];
    const float* Wl     = (const float*)d_in[4];
    const float* bl     = (const float*)d_in[5];
    const float* Wd     = (const float*)d_in[6];
    const float* bd     = (const float*)d_in[7];
    float* out = (float*)d_out;

    int*   done     = (int*)d_ws;
    float* hbuf     = (float*)d_ws + 4096;
    float* htop     = hbuf + (size_t)PP * LL * HH * BB;
    float* partials = htop + (size_t)TT * HH * BB;

    init_zero<<<16, 256, 0, stream>>>(done);
    lstm_pipeline<<<256, 512, 0, stream>>>(x, W0, b0, Wl, bl, done, hbuf, htop);
    epilogue<<<64, 128, 0, stream>>>(htop, Wd, bd, labels, out, partials);
    finalize<<<1, 64, 0, stream>>>(partials, out);
}

// Round 3
// 1477.399 us; speedup vs baseline: 4.0892x; 1.2264x over previous
//
#include <hip/hip_runtime.h>

#define TT 64   // timesteps
#define LL 64   // layers
#define BB 128  // batch
#define HH 64   // hidden

// Decomposition: 256 WGs = 64 layers x 2 batch-slices(64) x 2 col-halves(128 cols).
// 512 threads = 8 waves; wave w owns 16 cols = 4 units x 4 gates; lane = batch b.
// Weights wave-uniform -> s_load from reordered scratch Wre. h via 1 ds_read_b32/k.
//
// ws layout (floats):
//   flags : int[LL*2*2]            (latest finished t+1 per WG)   @ 0 (4096 floats resv)
//   Wre   : [LL][2ch][8w][128k][16] = 2,097,152                   (8 MB)
//   hbuf  : [2 slot][LL][2 s][64 u][64 b] = 1,048,576             (4 MB)
//   htop  : [TT][HH][BB] = 524,288                                (2 MB)
//   partials: [TT]

__device__ __forceinline__ float sigm(float x)  { return 1.f / (1.f + __expf(-x)); }
__device__ __forceinline__ float tanh_f(float x){ return 2.f / (1.f + __expf(-2.f*x)) - 1.f; }

__device__ __forceinline__ float gload(const float* p) {
    return __hip_atomic_load(p, __ATOMIC_RELAXED, __HIP_MEMORY_SCOPE_AGENT);
}
__device__ __forceinline__ void gstore(float* p, float v) {
    __hip_atomic_store(p, v, __ATOMIC_RELAXED, __HIP_MEMORY_SCOPE_AGENT);
}
__device__ __forceinline__ int fload(const int* p) {
    return __hip_atomic_load(p, __ATOMIC_RELAXED, __HIP_MEMORY_SCOPE_AGENT);
}
__device__ __forceinline__ void fstore(int* p, int v) {
    __hip_atomic_store(p, v, __ATOMIC_RELAXED, __HIP_MEMORY_SCOPE_AGENT);
}

__global__ __launch_bounds__(256, 1) void init_flags(int* flags) {
    int i = blockIdx.x * 256 + threadIdx.x;
    if (i < LL * 2 * 2) flags[i] = 0;
}

// Wre[l][ch][w][k][j]: j = u*4+gate, global col = gate*64 + ch*32 + w*4 + u.
// k<64: below-h weight rows; k>=64: own-h rows. l==0: k==0 = x row, 1..63 zero,
// 64+u -> W0 row 1+u.
__global__ __launch_bounds__(256, 1) void reorder_w(
    const float* __restrict__ W0, const float* __restrict__ Wl, float* __restrict__ Wre)
{
    int idx = blockIdx.x * 256 + threadIdx.x;
    if (idx >= LL * 2 * 8 * 128 * 16) return;
    int j  = idx & 15;
    int k  = (idx >> 4) & 127;
    int w  = (idx >> 11) & 7;
    int ch = (idx >> 14) & 1;
    int l  = idx >> 15;
    int gcol = (j & 3) * 64 + ch * 32 + w * 4 + (j >> 2);
    float v;
    if (l > 0)       v = Wl[((size_t)(l - 1) * 128 + k) * 256 + gcol];
    else if (k == 0) v = W0[gcol];
    else if (k < 64) v = 0.f;
    else             v = W0[(size_t)(k - 63) * 256 + gcol];
    Wre[idx] = v;
}

__global__ __launch_bounds__(512, 1) void lstm_pipeline(
    const float* __restrict__ x,    // [B][T][1]
    const float* __restrict__ b0,   // [256]
    const float* __restrict__ bl,   // [63][256]
    const float* __restrict__ Wre,
    int* __restrict__ flags,
    float* __restrict__ hbuf,
    float* __restrict__ htop)
{
    const int bx   = blockIdx.x;
    const int l    = bx >> 2;
    const int s    = (bx >> 1) & 1;
    const int ch   = bx & 1;
    const int tid  = threadIdx.x;
    const int wv   = __builtin_amdgcn_readfirstlane(tid >> 6);
    const int lane = tid & 63;      // batch index within slice

    __shared__ float hT[128][64];   // rows 0..63 below-h, 64..127 own-h
    __shared__ float xb[64][66];    // l==0 input staging (padded)

    const float* bsrc = l ? (bl + (l - 1) * 256) : b0;
    float bias[16];
#pragma unroll
    for (int j = 0; j < 16; ++j)
        bias[j] = bsrc[(j & 3) * 64 + ch * 32 + wv * 4 + (j >> 2)];

    if (l == 0) {
        for (int idx = tid; idx < 64 * 64; idx += 512)
            xb[idx >> 6][idx & 63] = x[((size_t)(s * 64 + (idx >> 6))) * TT + (idx & 63)];
    }
    __syncthreads();

    const float* wp = Wre + ((((size_t)l * 2 + ch) * 8 + wv) * 128) * 16;
#define FIDX(L, S, C) (((L) * 2 + (S)) * 2 + (C))
#define HB(SLOT, L, S) ((((size_t)(SLOT) * LL + (L)) * 2 + (S)) * 4096)

    float cst[4] = {};              // c-state: 4 units x 1 batch per thread

    for (int t = 0; t < TT; ++t) {
        float acc[16] = {};

        // ---------- Phase A: own-h(t-1), k = 64..127 ----------
        if (t > 0) {
            if (tid == 0)
                while (fload(&flags[FIDX(l, s, ch ^ 1)]) < t) {}
            __syncthreads();
            const float* own = hbuf + HB((t - 1) & 1, l, s);
            float r[8];
#pragma unroll
            for (int q = 0; q < 8; ++q) r[q] = gload(own + q * 512 + tid);
#pragma unroll
            for (int q = 0; q < 8; ++q) ((float*)hT)[4096 + q * 512 + tid] = r[q];
            __syncthreads();
#pragma unroll 4
            for (int k = 64; k < 128; ++k) {
                float h = hT[k][lane];
                const float4* w4 = (const float4*)(wp + k * 16);
                float4 wa = w4[0], wb = w4[1], wc = w4[2], wd = w4[3];
                acc[0]  = fmaf(wa.x, h, acc[0]);  acc[1]  = fmaf(wa.y, h, acc[1]);
                acc[2]  = fmaf(wa.z, h, acc[2]);  acc[3]  = fmaf(wa.w, h, acc[3]);
                acc[4]  = fmaf(wb.x, h, acc[4]);  acc[5]  = fmaf(wb.y, h, acc[5]);
                acc[6]  = fmaf(wb.z, h, acc[6]);  acc[7]  = fmaf(wb.w, h, acc[7]);
                acc[8]  = fmaf(wc.x, h, acc[8]);  acc[9]  = fmaf(wc.y, h, acc[9]);
                acc[10] = fmaf(wc.z, h, acc[10]); acc[11] = fmaf(wc.w, h, acc[11]);
                acc[12] = fmaf(wd.x, h, acc[12]); acc[13] = fmaf(wd.y, h, acc[13]);
                acc[14] = fmaf(wd.z, h, acc[14]); acc[15] = fmaf(wd.w, h, acc[15]);
            }
        }

        // ---------- Phase B: below-h(t), k = 0..63 ----------
        if (tid == 0) {
            if (l > 0) {
                while (fload(&flags[FIDX(l - 1, s, 0)]) < t + 1) {}
                while (fload(&flags[FIDX(l - 1, s, 1)]) < t + 1) {}
            }
            if (l < LL - 1 && t >= 2) {   // slot-reuse safety for layer-above readers
                while (fload(&flags[FIDX(l + 1, s, 0)]) < t - 1) {}
                while (fload(&flags[FIDX(l + 1, s, 1)]) < t - 1) {}
            }
        }
        __syncthreads();

        if (l > 0) {
            const float* below = hbuf + HB(t & 1, l - 1, s);
            float r[8];
#pragma unroll
            for (int q = 0; q < 8; ++q) r[q] = gload(below + q * 512 + tid);
#pragma unroll
            for (int q = 0; q < 8; ++q) ((float*)hT)[q * 512 + tid] = r[q];
            __syncthreads();
#pragma unroll 4
            for (int k = 0; k < 64; ++k) {
                float h = hT[k][lane];
                const float4* w4 = (const float4*)(wp + k * 16);
                float4 wa = w4[0], wb = w4[1], wc = w4[2], wd = w4[3];
                acc[0]  = fmaf(wa.x, h, acc[0]);  acc[1]  = fmaf(wa.y, h, acc[1]);
                acc[2]  = fmaf(wa.z, h, acc[2]);  acc[3]  = fmaf(wa.w, h, acc[3]);
                acc[4]  = fmaf(wb.x, h, acc[4]);  acc[5]  = fmaf(wb.y, h, acc[5]);
                acc[6]  = fmaf(wb.z, h, acc[6]);  acc[7]  = fmaf(wb.w, h, acc[7]);
                acc[8]  = fmaf(wc.x, h, acc[8]);  acc[9]  = fmaf(wc.y, h, acc[9]);
                acc[10] = fmaf(wc.z, h, acc[10]); acc[11] = fmaf(wc.w, h, acc[11]);
                acc[12] = fmaf(wd.x, h, acc[12]); acc[13] = fmaf(wd.y, h, acc[13]);
                acc[14] = fmaf(wd.z, h, acc[14]); acc[15] = fmaf(wd.w, h, acc[15]);
            }
        } else {
            float xv = xb[lane][t];
            const float4* w4 = (const float4*)(wp);   // k = 0 row
            float4 wa = w4[0], wb = w4[1], wc = w4[2], wd = w4[3];
            acc[0]  = fmaf(wa.x, xv, acc[0]);  acc[1]  = fmaf(wa.y, xv, acc[1]);
            acc[2]  = fmaf(wa.z, xv, acc[2]);  acc[3]  = fmaf(wa.w, xv, acc[3]);
            acc[4]  = fmaf(wb.x, xv, acc[4]);  acc[5]  = fmaf(wb.y, xv, acc[5]);
            acc[6]  = fmaf(wb.z, xv, acc[6]);  acc[7]  = fmaf(wb.w, xv, acc[7]);
            acc[8]  = fmaf(wc.x, xv, acc[8]);  acc[9]  = fmaf(wc.y, xv, acc[9]);
            acc[10] = fmaf(wc.z, xv, acc[10]); acc[11] = fmaf(wc.w, xv, acc[11]);
            acc[12] = fmaf(wd.x, xv, acc[12]); acc[13] = fmaf(wd.y, xv, acc[13]);
            acc[14] = fmaf(wd.z, xv, acc[14]); acc[15] = fmaf(wd.w, xv, acc[15]);
        }

        // ---------- cell + h2 store ----------
        float* dst = hbuf + HB(t & 1, l, s);
#pragma unroll
        for (int u = 0; u < 4; ++u) {
            float zi = acc[u * 4 + 0] + bias[u * 4 + 0];
            float zj = acc[u * 4 + 1] + bias[u * 4 + 1];
            float zf = acc[u * 4 + 2] + bias[u * 4 + 2];
            float zo = acc[u * 4 + 3] + bias[u * 4 + 3];
            float c2 = cst[u] * sigm(zf) + sigm(zi) * tanh_f(zj);
            cst[u] = c2;
            float h2 = tanh_f(c2) * sigm(zo);
            int U = ch * 32 + wv * 4 + u;
            gstore(dst + U * 64 + lane, h2);
            if (l == LL - 1)
                gstore(htop + ((size_t)t * HH + U) * BB + s * 64 + lane, h2);
        }
        __builtin_amdgcn_s_waitcnt(0);   // release: stores at IC before flag
        __syncthreads();
        if (tid == 0) fstore(&flags[FIDX(l, s, ch)], t + 1);
    }
}

__global__ __launch_bounds__(128, 1) void epilogue(
    const float* __restrict__ htop, const float* __restrict__ Wd,
    const float* __restrict__ bd, const float* __restrict__ labels,
    float* __restrict__ out, float* __restrict__ partials)
{
    int t = blockIdx.x, b = threadIdx.x;  // 64 blocks x 128 threads
    float s = 0.f;
    for (int h = 0; h < HH; ++h)
        s = fmaf(htop[(size_t)t * HH * BB + h * BB + b], Wd[t * HH + h], s);
    s += bd[t];
    s = fmaxf(s, 0.f);
    out[b * TT + t] = s;                  // pred is [B][T][1]
    float d = labels[b * TT + t] - s;
    float e = d * d;
#pragma unroll
    for (int off = 32; off > 0; off >>= 1) e += __shfl_down(e, off, 64);
    __shared__ float ws2[2];
    if ((b & 63) == 0) ws2[b >> 6] = e;
    __syncthreads();
    if (b == 0) partials[t] = ws2[0] + ws2[1];
}

__global__ __launch_bounds__(64, 1) void finalize(const float* __restrict__ partials,
                                                  float* __restrict__ out) {
    int i = threadIdx.x;
    float v = partials[i];
#pragma unroll
    for (int off = 32; off > 0; off >>= 1) v += __shfl_down(v, off, 64);
    if (i == 0) out[BB * TT] = v * (1.f / (BB * TT));
}

extern "C" void kernel_launch(void* const* d_in, const int* in_sizes, int n_in,
                              void* d_out, int out_size, void* d_ws, size_t ws_size,
                              hipStream_t stream) {
    const float* x      = (const float*)d_in[0];
    const float* labels = (const float*)d_in[1];
    const float* W0     = (const float*)d_in[2];
    const float* b0     = (const float*)d_in[3];
    const float* Wl     = (const float*)d_in[4];
    const float* bl     = (const float*)d_in[5];
    const float* Wd     = (const float*)d_in[6];
    const float* bd     = (const float*)d_in[7];
    float* out = (float*)d_out;

    int*   flags    = (int*)d_ws;
    float* Wre      = (float*)d_ws + 4096;
    float* hbuf     = Wre + (size_t)LL * 2 * 8 * 128 * 16;
    float* htop     = hbuf + (size_t)2 * LL * 2 * 64 * 64;
    float* partials = htop + (size_t)TT * HH * BB;

    init_flags<<<1, 256, 0, stream>>>(flags);
    reorder_w<<<8192, 256, 0, stream>>>(W0, Wl, Wre);
    lstm_pipeline<<<256, 512, 0, stream>>>(x, b0, bl, Wre, flags, hbuf, htop);
    epilogue<<<64, 128, 0, stream>>>(htop, Wd, bd, labels, out, partials);
    finalize<<<1, 64, 0, stream>>>(partials, out);
}

// Round 4
// 805.940 us; speedup vs baseline: 7.4961x; 1.8331x over previous
//
#include <hip/hip_runtime.h>
#include <hip/hip_bf16.h>

#define TT 64   // timesteps
#define LL 64   // layers
#define BB 128  // batch
#define HH 64   // hidden

typedef short v8s __attribute__((ext_vector_type(8)));   // 8 bf16 = 4 VGPR (MFMA A/B frag)
typedef float v4f __attribute__((ext_vector_type(4)));   // MFMA C/D frag

// ws layout (bytes):
//   flags : int[LL*2]                     @ 0      (16 KB reserved)
//   Wre   : ushort[LL][2ng][32f][64ln][8] @ 16K    (4 MB)  bf16 B-fragments
//   hglob : ushort[4slot][LL][2s][64u][64b] (4 MB)         bf16 h, [u][b] rows
//   htop  : float[TT][HH][BB]             (2 MB)
//   partials: float[TT]
//
// Coherence (validated R2/R3): relaxed agent-scope atomics (sc1 -> Infinity
// Cache, no L2 flush instrs). Release = s_waitcnt(0) before flag; acquire =
// flag poll + barrier before data loads.

__device__ __forceinline__ float sigm(float x)  { return 1.f / (1.f + __expf(-x)); }
__device__ __forceinline__ float tanh_f(float x){ return 2.f / (1.f + __expf(-2.f*x)) - 1.f; }

__device__ __forceinline__ int fload(const int* p) {
    return __hip_atomic_load(p, __ATOMIC_RELAXED, __HIP_MEMORY_SCOPE_AGENT);
}
__device__ __forceinline__ void fstore(int* p, int v) {
    __hip_atomic_store(p, v, __ATOMIC_RELAXED, __HIP_MEMORY_SCOPE_AGENT);
}
__device__ __forceinline__ unsigned long long gload64(const void* p) {
    return __hip_atomic_load((const unsigned long long*)p, __ATOMIC_RELAXED,
                             __HIP_MEMORY_SCOPE_AGENT);
}
__device__ __forceinline__ void gstore64(void* p, unsigned long long v) {
    __hip_atomic_store((unsigned long long*)p, v, __ATOMIC_RELAXED,
                       __HIP_MEMORY_SCOPE_AGENT);
}
__device__ __forceinline__ void gstoref(float* p, float v) {
    __hip_atomic_store(p, v, __ATOMIC_RELAXED, __HIP_MEMORY_SCOPE_AGENT);
}
__device__ __forceinline__ unsigned short f2bf(float f) {
    __hip_bfloat16 b = __float2bfloat16(f);   // RNE
    return *(unsigned short*)&b;
}

__global__ __launch_bounds__(256, 1) void init_flags(int* flags) {
    int i = blockIdx.x * 256 + threadIdx.x;
    if (i < LL * 2) flags[i] = 0;
}

// Pack weights as bf16 MFMA B-fragments.
// Layout: Wre[l][ng][f][ln][j], f = tn*4+kf, tn = ug*4+ga.
// B[k][n]: k = kf*32 + (ln>>4)*8 + j, n-col gcol = ga*64 + ng*32 + ug*16 + (ln&15).
// k<64: below-h rows; k>=64: own-h rows. l==0: k==0 -> x row (W0[0]), k=1..63 -> 0,
// k>=64 -> W0[k-63].
__global__ __launch_bounds__(256, 1) void reorder_w(
    const float* __restrict__ W0, const float* __restrict__ Wl,
    unsigned short* __restrict__ Wre)
{
    int idx = blockIdx.x * 256 + threadIdx.x;
    if (idx >= LL * 2 * 32 * 64 * 8) return;
    int j  = idx & 7;
    int ln = (idx >> 3) & 63;
    int f  = (idx >> 9) & 31;
    int ng = (idx >> 14) & 1;
    int l  = idx >> 15;
    int kf = f & 3, tn = f >> 2;
    int ga = tn & 3, ug = tn >> 2;
    int k    = kf * 32 + (ln >> 4) * 8 + j;
    int gcol = ga * 64 + ng * 32 + ug * 16 + (ln & 15);
    float v;
    if (l > 0)       v = Wl[((size_t)(l - 1) * 128 + k) * 256 + gcol];
    else if (k == 0) v = W0[gcol];
    else if (k < 64) v = 0.f;
    else             v = W0[(size_t)(k - 63) * 256 + gcol];
    Wre[idx] = f2bf(v);
}

__global__ __launch_bounds__(512, 2) void lstm_pipeline(
    const float* __restrict__ x,    // [B][T]
    const float* __restrict__ b0,   // [256]
    const float* __restrict__ bl,   // [63][256]
    const unsigned short* __restrict__ Wre,
    int* __restrict__ flags,
    unsigned short* __restrict__ hglob,
    float* __restrict__ htop)
{
    const int l   = blockIdx.x >> 1;
    const int s   = blockIdx.x & 1;
    const int tid = threadIdx.x;
    const int wv  = tid >> 6;        // wave 0..7
    const int ln  = tid & 63;
    const int mt  = wv & 3;          // m-tile: batch rows mt*16..+16
    const int ng  = wv >> 2;         // n-group: cols ng*128..+128
    const int lr  = ln & 15;
    const int qd  = ln >> 4;

    __shared__ unsigned short hsm[64 * 136]; // [b][k 0..127 + 8 pad], rows 272B (16B-mult)
    __shared__ float xbuf[64 * 65];          // l==0 input staging (padded)

    for (int i = tid; i < 64 * 136 / 2; i += 512) ((unsigned int*)hsm)[i] = 0u;

    // ---- persistent B fragments: 32 frags x 4 VGPR = 128 VGPRs ----
    v8s bfr[32];
    const unsigned short* wbase = Wre + (((size_t)l * 2 + ng) * 32) * 512;
#pragma unroll
    for (int f = 0; f < 32; ++f)
        bfr[f] = *(const v8s*)(wbase + ((size_t)f * 64 + ln) * 8);

    const float* bsrc = l ? (bl + (l - 1) * 256) : b0;
    float bias[8];
#pragma unroll
    for (int tn = 0; tn < 8; ++tn) {
        int ga = tn & 3, ug = tn >> 2;
        bias[tn] = bsrc[ga * 64 + ng * 32 + ug * 16 + lr];
    }

    if (l == 0) {
        for (int idx = tid; idx < 4096; idx += 512)
            xbuf[(idx >> 6) * 65 + (idx & 63)] =
                x[((size_t)(s * 64 + (idx >> 6))) * TT + (idx & 63)];
    }
    __syncthreads();

    float cst[8];                    // c-state: [ug][reg]
#pragma unroll
    for (int i = 0; i < 8; ++i) cst[i] = 0.f;

    const int fl_below = (l - 1) * 2 + s;
    const int fl_above = (l + 1) * 2 + s;
    const int fl_own   = l * 2 + s;

    for (int t = 0; t < TT; ++t) {
        // l==0: x_t into k=0 of every row (prev-step A-reads finished at last barrier)
        if (l == 0 && tid < 64)
            hsm[tid * 136 + 0] = f2bf(xbuf[tid * 65 + t]);

        if (tid == 0) {
            if (l > 0)               while (fload(&flags[fl_below]) < t + 1) {}
            if (l < LL - 1 && t >= 4) while (fload(&flags[fl_above]) < t - 3) {}
        }
        __syncthreads();

        // ---- stage below-h: hglob[t&3][l-1][s] is [u][b]; transpose into rows k=0..63
        if (l > 0) {
            const unsigned short* src =
                hglob + ((((size_t)(t & 3) * LL + (l - 1)) * 2 + s) * 4096);
            unsigned long long d0 = gload64(src + tid * 8);
            unsigned long long d1 = gload64(src + tid * 8 + 4);
            unsigned short tmp[8];
            *(unsigned long long*)&tmp[0] = d0;
            *(unsigned long long*)&tmp[4] = d1;
            int u   = tid >> 3;
            int bb0 = (tid & 7) * 8;
#pragma unroll
            for (int jj = 0; jj < 8; ++jj)
                hsm[(bb0 + jj) * 136 + u] = tmp[jj];
        }
        __syncthreads();

        // ---- A fragments (16B-aligned ds_read_b128, bandwidth-floor pattern) ----
        v8s afr[4];
#pragma unroll
        for (int kf = 0; kf < 4; ++kf)
            afr[kf] = *(const v8s*)&hsm[(mt * 16 + lr) * 136 + kf * 32 + qd * 8];

        v4f acc[8];
#pragma unroll
        for (int i = 0; i < 8; ++i) acc[i] = (v4f){0.f, 0.f, 0.f, 0.f};
#pragma unroll
        for (int tn = 0; tn < 8; ++tn)
#pragma unroll
            for (int kf = 0; kf < 4; ++kf)
                acc[tn] = __builtin_amdgcn_mfma_f32_16x16x32_bf16(
                    afr[kf], bfr[tn * 4 + kf], acc[tn], 0, 0, 0);

        __syncthreads();   // all waves' A-reads done before own-region overwrite

        // ---- cell (thread-local: 4 gates resident) + h2 stores ----
        unsigned short* dstg =
            hglob + ((((size_t)(t & 3) * LL + l) * 2 + s) * 4096);
#pragma unroll
        for (int ug = 0; ug < 2; ++ug) {
            const int u = ng * 32 + ug * 16 + lr;
            unsigned short hp[4];
#pragma unroll
            for (int r = 0; r < 4; ++r) {
                float zi = acc[ug * 4 + 0][r] + bias[ug * 4 + 0];
                float zj = acc[ug * 4 + 1][r] + bias[ug * 4 + 1];
                float zf = acc[ug * 4 + 2][r] + bias[ug * 4 + 2];
                float zo = acc[ug * 4 + 3][r] + bias[ug * 4 + 3];
                float c2 = cst[ug * 4 + r] * sigm(zf) + sigm(zi) * tanh_f(zj);
                cst[ug * 4 + r] = c2;
                float h2 = tanh_f(c2) * sigm(zo);
                hp[r] = f2bf(h2);
                int b = mt * 16 + qd * 4 + r;
                hsm[b * 136 + 64 + u] = hp[r];               // own region k=64+u
                if (l == LL - 1)
                    gstoref(htop + ((size_t)t * HH + u) * BB + s * 64 + b, h2);
            }
            if (l < LL - 1) {
                unsigned long long pk =
                    (unsigned long long)hp[0] | ((unsigned long long)hp[1] << 16) |
                    ((unsigned long long)hp[2] << 32) | ((unsigned long long)hp[3] << 48);
                gstore64(dstg + u * 64 + mt * 16 + qd * 4, pk);
            }
        }
        __builtin_amdgcn_s_waitcnt(0);   // release: h2 at IC before flag
        __syncthreads();
        if (tid == 0) fstore(&flags[fl_own], t + 1);
    }
}

__global__ __launch_bounds__(128, 1) void epilogue(
    const float* __restrict__ htop, const float* __restrict__ Wd,
    const float* __restrict__ bd, const float* __restrict__ labels,
    float* __restrict__ out, float* __restrict__ partials)
{
    int t = blockIdx.x, b = threadIdx.x;  // 64 blocks x 128 threads
    float s = 0.f;
    for (int h = 0; h < HH; ++h)
        s = fmaf(htop[(size_t)t * HH * BB + h * BB + b], Wd[t * HH + h], s);
    s += bd[t];
    s = fmaxf(s, 0.f);
    out[b * TT + t] = s;                  // pred [B][T][1]
    float d = labels[b * TT + t] - s;
    float e = d * d;
#pragma unroll
    for (int off = 32; off > 0; off >>= 1) e += __shfl_down(e, off, 64);
    __shared__ float ws2[2];
    if ((b & 63) == 0) ws2[b >> 6] = e;
    __syncthreads();
    if (b == 0) partials[t] = ws2[0] + ws2[1];
}

__global__ __launch_bounds__(64, 1) void finalize(const float* __restrict__ partials,
                                                  float* __restrict__ out) {
    int i = threadIdx.x;
    float v = partials[i];
#pragma unroll
    for (int off = 32; off > 0; off >>= 1) v += __shfl_down(v, off, 64);
    if (i == 0) out[BB * TT] = v * (1.f / (BB * TT));
}

extern "C" void kernel_launch(void* const* d_in, const int* in_sizes, int n_in,
                              void* d_out, int out_size, void* d_ws, size_t ws_size,
                              hipStream_t stream) {
    const float* x      = (const float*)d_in[0];
    const float* labels = (const float*)d_in[1];
    const float* W0     = (const float*)d_in[2];
    const float* b0     = (const float*)d_in[3];
    const float* Wl     = (const float*)d_in[4];
    const float* bl     = (const float*)d_in[5];
    const float* Wd     = (const float*)d_in[6];
    const float* bd     = (const float*)d_in[7];
    float* out = (float*)d_out;

    char* base = (char*)d_ws;
    int*            flags = (int*)base;
    unsigned short* Wre   = (unsigned short*)(base + 16384);
    unsigned short* hglob = Wre + (size_t)LL * 2 * 32 * 64 * 8;      // +4 MB
    float*          htop  = (float*)(hglob + (size_t)4 * LL * 2 * 4096); // +4 MB
    float*          partials = htop + (size_t)TT * HH * BB;

    init_flags<<<1, 256, 0, stream>>>(flags);
    reorder_w<<<8192, 256, 0, stream>>>(W0, Wl, Wre);
    lstm_pipeline<<<128, 512, 0, stream>>>(x, b0, bl, Wre, flags, hglob, htop);
    epilogue<<<64, 128, 0, stream>>>(htop, Wd, bd, labels, out, partials);
    finalize<<<1, 64, 0, stream>>>(partials, out);
}